// Round 7
// baseline (89.286 us; speedup 1.0000x reference)
//
#include <hip/hip_runtime.h>
#include <hip/hip_bf16.h>

typedef float v2f __attribute__((ext_vector_type(2)));
typedef short short8 __attribute__((ext_vector_type(8)));
typedef float f32x4 __attribute__((ext_vector_type(4)));

#define NCLS  10
#define FEATN 3920
#define GIMG  8            // images per block; grid = 1024 -> 4 blocks/CU
#define RSTR  532          // LDS row stride in dwords
// Permuted K, padded to 3936 = 123 kb (kb = 32 k).
// Tile t in {0,1,2}: patches [48t,48t+48): filter 768 k, sampler 192 k (30 kb).
// Tile 3: patches [144,196): filter 832 k, sampler 208 k, pad 16 k (33 kb).
// In this layout: filter korig = 768t + u;  sampler korig = 3136 + 192t + (u - np*16)
// -> every (kb,lane) B-fragment is 8 CONSECUTIVE fp32 of fc_w: convert at load time.

__device__ __forceinline__ unsigned packbf(float a, float b) {
    __hip_bfloat162 h = __float22bfloat162_rn(float2{a, b});
    unsigned u; __builtin_memcpy(&u, &h, 4); return u;
}

// sin/cos of (0.5*v) via native v_sin_f32/v_cos_f32 (input in revolutions; v in [0,1))
__device__ __forceinline__ void fastsc(float v, float& s, float& c) {
    const float r = v * 0.07957747154594767f;   // 0.5 / (2*pi)
#if __has_builtin(__builtin_amdgcn_sinf)
    s = __builtin_amdgcn_sinf(r);
    c = __builtin_amdgcn_cosf(r);
#else
    s = __sinf(0.5f * v);
    c = __cosf(0.5f * v);
#endif
}

__global__ __launch_bounds__(256, 4)
void quanv_all(const float* __restrict__ x,
               const float* __restrict__ fc_w,
               const float* __restrict__ fc_b,
               float* __restrict__ out) {
    __shared__ __align__(16) unsigned lds[GIMG * RSTR];     // 17024 B
    const int tid  = threadIdx.x;
    const int lane = tid & 63;
    const int wave = tid >> 6;
    const int img0 = blockIdx.x * GIMG;
    const float* base = x + (size_t)img0 * 784;
    const int am  = lane & 15;
    const int ach = lane >> 4;
    const unsigned aoff = (unsigned)((am & 7) * RSTR + ach * 4);  // dup rows 8..15
    const bool bnv = am < NCLS;                                   // B row (class) valid
    const float* wrow = fc_w + (size_t)(bnv ? am : 0) * FEATN;
    const int ach8 = ach * 8;

    f32x4 acc = {0.f, 0.f, 0.f, 0.f};

    // ---- tile-0 pixel load ----
    float2 pc[4], pn[4];
    int lpC, qC; bool actC;
    {
        actC = tid < 48 * 4;
        const int tt = actC ? tid : 0;
        qC = tt / 48; lpC = tt - qC * 48;
        const int pi = lpC / 14, pj = lpC - pi * 14;
        const int off = pi * 56 + pj * 2;
        const float* iA = base + (size_t)(2 * qC) * 784;
        pc[0] = *reinterpret_cast<const float2*>(iA + off);
        pc[1] = *reinterpret_cast<const float2*>(iA + off + 28);
        pc[2] = *reinterpret_cast<const float2*>(iA + 784 + off);
        pc[3] = *reinterpret_cast<const float2*>(iA + 784 + off + 28);
    }

    #pragma unroll
    for (int t = 0; t < 4; ++t) {
        const int np   = (t == 3) ? 52 : 48;
        const int nkb  = (t == 3) ? 33 : 30;
        const int np16 = np * 16, np20 = np * 20;
        const int fb   = 768 * t, sb = 3136 + 192 * t;

        if (actC) {
            const float2 tA = pc[0], bA = pc[1], tB = pc[2], bB = pc[3];
            float sA0,cA0,sA1,cA1,sA2,cA2,sA3,cA3;
            float sB0,cB0,sB1,cB1,sB2,cB2,sB3,cB3;
            fastsc(tA.x, sA0, cA0); fastsc(tA.y, sA1, cA1);
            fastsc(bA.x, sA2, cA2); fastsc(bA.y, sA3, cA3);
            fastsc(tB.x, sB0, cB0); fastsc(tB.y, sB1, cB1);
            fastsc(bB.x, sB2, cB2); fastsc(bB.y, sB3, cB3);

            const v2f c0 = {cA0, cB0}, s0 = {sA0, sB0};
            const v2f c1 = {cA1, cB1}, s1 = {sA1, sB1};
            v2f a00 = c0 * c1, a01 = c0 * s1, a10 = s0 * c1, a11 = s0 * s1;
            #pragma unroll
            for (int r = 0; r < 8; ++r) {
                const v2f b10 = a11, b11 = a10;          // CX(0,1)
                const v2f n00 = c0 * a00 - s0 * b10;     // RY(p0)
                const v2f n01 = c0 * a01 - s0 * b11;
                const v2f n10 = s0 * a00 + c0 * b10;
                const v2f n11 = s0 * a01 + c0 * b11;
                a00 = n00; a01 = n01; a10 = n10; a11 = n11;
            }
            v2f P2[4];
            P2[0] = a00 * a00; P2[1] = a01 * a01; P2[2] = a10 * a10; P2[3] = a11 * a11;
            const v2f t2c = {cA2*cA2, cB2*cB2}, t2s = {sA2*sA2, sB2*sB2};
            const v2f t3c = {cA3*cA3, cB3*cB3}, t3s = {sA3*sA3, sB3*sB3};
            v2f T[4];
            T[0] = t2c * t3c; T[1] = t2c * t3s; T[2] = t2s * t3c; T[3] = t2s * t3s;

            unsigned dA[8], dB[8];
            #pragma unroll
            for (int m = 0; m < 4; ++m) {
                const v2f f0 = P2[m] * T[0], f1 = P2[m] * T[1];
                const v2f f2 = P2[m] * T[2], f3 = P2[m] * T[3];
                dA[2*m]   = packbf(f0.x, f1.x); dA[2*m+1] = packbf(f2.x, f3.x);
                dB[2*m]   = packbf(f0.y, f1.y); dB[2*m+1] = packbf(f2.y, f3.y);
            }
            const v2f sa = s0 * s0, sb2 = t3s;           // sampler: p0, p3
            const v2f na = 1.0f - sa, nb = 1.0f - sb2;
            const v2f e0 = na * nb, e1 = na * sb2, e2 = sa * nb, e3 = sa * sb2;

            unsigned* rowA = lds + (2 * qC) * RSTR;
            unsigned* rowB = rowA + RSTR;
            *reinterpret_cast<uint4*>(rowA + lpC * 8)     = uint4{dA[0], dA[1], dA[2], dA[3]};
            *reinterpret_cast<uint4*>(rowA + lpC * 8 + 4) = uint4{dA[4], dA[5], dA[6], dA[7]};
            *reinterpret_cast<uint2*>(rowA + np * 8 + lpC * 2) =
                uint2{packbf(e0.x, e1.x), packbf(e2.x, e3.x)};
            *reinterpret_cast<uint4*>(rowB + lpC * 8)     = uint4{dB[0], dB[1], dB[2], dB[3]};
            *reinterpret_cast<uint4*>(rowB + lpC * 8 + 4) = uint4{dB[4], dB[5], dB[6], dB[7]};
            *reinterpret_cast<uint2*>(rowB + np * 8 + lpC * 2) =
                uint2{packbf(e0.y, e1.y), packbf(e2.y, e3.y)};
        }
        if (t == 3 && tid < 64)   // zero A-pad k 3920..3935 (dwords 520..527, rows 0..7)
            lds[(tid >> 3) * RSTR + 520 + (tid & 7)] = 0u;

        // ---- prefetch next tile's pixels (overlaps barrier + MFMA phase) ----
        int lpN = 0, qN = 0; bool actN = false;
        if (t < 3) {
            const int npN = (t + 1 == 3) ? 52 : 48;
            actN = tid < npN * 4;
            const int tt = actN ? tid : 0;
            qN = tt / npN; lpN = tt - qN * npN;
            const int p = 48 * (t + 1) + lpN;
            const int pi = p / 14, pj = p - pi * 14;
            const int off = pi * 56 + pj * 2;
            const float* iA = base + (size_t)(2 * qN) * 784;
            pn[0] = *reinterpret_cast<const float2*>(iA + off);
            pn[1] = *reinterpret_cast<const float2*>(iA + off + 28);
            pn[2] = *reinterpret_cast<const float2*>(iA + 784 + off);
            pn[3] = *reinterpret_cast<const float2*>(iA + 784 + off + 28);
        }
        __syncthreads();

        // ---- MFMA loop: A from LDS, B straight from fc_w (fp32 -> bf16 inline) ----
        for (int kb = wave; kb < nkb; kb += 4) {
            const short8 a = *reinterpret_cast<const short8*>(lds + aoff + kb * 16);
            const int u = kb * 32 + ach8;
            const bool val = bnv && (u < np20);
            const int addr = val ? ((u < np16) ? fb + u : sb + (u - np16)) : 0;
            float4 wa = *reinterpret_cast<const float4*>(wrow + addr);
            float4 wb = *reinterpret_cast<const float4*>(wrow + addr + 4);
            if (!val) { wa = float4{0.f,0.f,0.f,0.f}; wb = float4{0.f,0.f,0.f,0.f}; }
            const uint4 bu{packbf(wa.x, wa.y), packbf(wa.z, wa.w),
                           packbf(wb.x, wb.y), packbf(wb.z, wb.w)};
            short8 b; __builtin_memcpy(&b, &bu, 16);
            acc = __builtin_amdgcn_mfma_f32_16x16x32_bf16(a, b, acc, 0, 0, 0);
        }
        __syncthreads();

        pc[0] = pn[0]; pc[1] = pn[1]; pc[2] = pn[2]; pc[3] = pn[3];
        lpC = lpN; qC = qN; actC = actN;
    }

    // ---- epilogue: combine 4 waves' K-split accs, bias, log-softmax ----
    float* f = reinterpret_cast<float*>(lds);
    f[wave * 256 +   0 + lane] = acc[0];
    f[wave * 256 +  64 + lane] = acc[1];
    f[wave * 256 + 128 + lane] = acc[2];
    f[wave * 256 + 192 + lane] = acc[3];
    __syncthreads();
    if (tid < GIMG * NCLS) {
        const int g = tid / NCLS, c = tid - g * NCLS;
        const int li = ((g >> 2) << 4) + c;   // D: col=lane&15, row=(lane>>4)*4+reg
        const int ri = (g & 3) << 6;
        float v = f[ri + li] + f[256 + ri + li] + f[512 + ri + li] + f[768 + ri + li];
        f[1024 + tid] = v + fc_b[c];
    }
    __syncthreads();
    if (tid < GIMG * NCLS) {
        const int g = tid / NCLS, c = tid - g * NCLS;
        const float* lg = f + 1024 + g * NCLS;
        float m = -1e30f;
        #pragma unroll
        for (int k = 0; k < NCLS; ++k) m = fmaxf(m, lg[k]);
        float ss = 0.f;
        #pragma unroll
        for (int k = 0; k < NCLS; ++k) ss += __expf(lg[k] - m);
        out[(size_t)(img0 + g) * NCLS + c] = lg[c] - m - __logf(ss);
    }
}

extern "C" void kernel_launch(void* const* d_in, const int* in_sizes, int n_in,
                              void* d_out, int out_size, void* d_ws, size_t ws_size,
                              hipStream_t stream) {
    const float* x    = (const float*)d_in[0];
    const float* fc_w = (const float*)d_in[1];
    const float* fc_b = (const float*)d_in[2];
    float* out = (float*)d_out;
    const int B = in_sizes[0] / 784;            // 8192
    const int grid = B / GIMG;                  // 1024
    quanv_all<<<grid, 256, 0, stream>>>(x, fc_w, fc_b, out);
}

// Round 8
// 82.326 us; speedup vs baseline: 1.0845x; 1.0845x over previous
//
#include <hip/hip_runtime.h>
#include <hip/hip_bf16.h>

typedef float v2f __attribute__((ext_vector_type(2)));
typedef short short8 __attribute__((ext_vector_type(8)));
typedef float f32x4 __attribute__((ext_vector_type(4)));

#define NCLS  10
#define FEATN 3920
#define GIMG  8            // images per block; grid = 1024 -> 4 blocks/CU
#define RSTR  532          // LDS row stride in dwords
#define LDSN  (GIMG * RSTR)
// Permuted K, padded to 3936 = 123 kb (kb = 32 k).
// Tile t in {0,1,2}: patches [48t,48t+48): filter 768 k, sampler 192 k (30 kb).
// Tile 3: patches [144,196): filter 832 k, sampler 208 k, pad 16 k (33 kb).
// Double-buffered LDS: tile t lives in buffer t&1 -> ONE barrier per tile.
// Safety: at barrier B_t every wave has finished tile (t-1)'s MFMA reads
// (program order), so tile t+1 may overwrite buffer (t+1)&1 after B_t.

__device__ __forceinline__ unsigned packbf(float a, float b) {
    __hip_bfloat162 h = __float22bfloat162_rn(float2{a, b});
    unsigned u; __builtin_memcpy(&u, &h, 4); return u;
}

// sin/cos of (0.5*v) via native v_sin_f32/v_cos_f32 (input in revolutions; v in [0,1))
__device__ __forceinline__ void fastsc(float v, float& s, float& c) {
    const float r = v * 0.07957747154594767f;   // 0.5 / (2*pi)
#if __has_builtin(__builtin_amdgcn_sinf)
    s = __builtin_amdgcn_sinf(r);
    c = __builtin_amdgcn_cosf(r);
#else
    s = __sinf(0.5f * v);
    c = __cosf(0.5f * v);
#endif
}

// ---- pre-pass: W fp32 -> bf16, MFMA B-fragment order, permuted K ----
__global__ void conv_w(const float* __restrict__ fc_w, __hip_bfloat16* __restrict__ ws) {
    const int id = blockIdx.x * 256 + threadIdx.x;          // 0..62975
    if (id >= 123 * 512) return;
    const int kb = id >> 9, r = id & 511, l = r >> 3, j0 = r & 7;
    const int n  = l & 15;
    const int kk = kb * 32 + ((l >> 4) << 3) + j0;          // new-layout k
    float w = 0.f;
    if (n < NCLS) {
        const int t    = (kk < 2880) ? kk / 960 : 3;
        const int base = 960 * t;
        const int P0   = 48 * t;
        const int np   = (t == 3) ? 52 : 48;
        const int u    = kk - base;
        int korig = -1;
        if (u < np * 16) {
            korig = 16 * (P0 + (u >> 4)) + (u & 15);        // filter feature
        } else {
            const int v = u - np * 16;
            if (v < np * 4) korig = 3136 + 4 * (P0 + (v >> 2)) + (v & 3);  // sampler
        }
        if (korig >= 0) w = fc_w[n * FEATN + korig];
    }
    ws[id] = __float2bfloat16(w);
}

__global__ __launch_bounds__(256, 4)
void quanv_mfma(const float* __restrict__ x,
                const short* __restrict__ wsb,     // bf16 bits, B-fragment order
                const float* __restrict__ fc_b,
                float* __restrict__ out) {
    __shared__ __align__(16) unsigned lds[2 * LDSN];        // 34048 B -> 4 blocks/CU
    const int tid  = threadIdx.x;
    const int lane = tid & 63;
    const int wave = tid >> 6;
    const int img0 = blockIdx.x * GIMG;
    const float* base = x + (size_t)img0 * 784;
    const int am  = lane & 15;
    const int ach = lane >> 4;
    const unsigned aoff = (unsigned)((am & 7) * RSTR + ach * 4);  // dup rows 8..15

    // zero tile-3 pad (buffer 1, rows 0..7, dwords 520..527) once
    if (tid < 64) lds[LDSN + (tid >> 3) * RSTR + 520 + (tid & 7)] = 0u;

    // ---- tile-0 pixel load ----
    float2 pc[4], pn[4];
    int lpC, qC; bool actC;
    {
        actC = tid < 48 * 4;
        const int tt = actC ? tid : 0;
        qC = tt / 48; lpC = tt - qC * 48;
        const int pi = lpC / 14, pj = lpC - pi * 14;
        const int off = pi * 56 + pj * 2;
        const float* iA = base + (size_t)(2 * qC) * 784;
        pc[0] = *reinterpret_cast<const float2*>(iA + off);
        pc[1] = *reinterpret_cast<const float2*>(iA + off + 28);
        pc[2] = *reinterpret_cast<const float2*>(iA + 784 + off);
        pc[3] = *reinterpret_cast<const float2*>(iA + 784 + off + 28);
    }

    f32x4 acc = {0.f, 0.f, 0.f, 0.f};

    #pragma unroll
    for (int t = 0; t < 4; ++t) {
        const int np  = (t == 3) ? 52 : 48;
        const int nkb = (t == 3) ? 33 : 30;
        const int kbb = 30 * t;
        unsigned* buf = lds + (t & 1) * LDSN;

        if (actC) {
            const float2 tA = pc[0], bA = pc[1], tB = pc[2], bB = pc[3];
            float sA0,cA0,sA1,cA1,sA2,cA2,sA3,cA3;
            float sB0,cB0,sB1,cB1,sB2,cB2,sB3,cB3;
            fastsc(tA.x, sA0, cA0); fastsc(tA.y, sA1, cA1);
            fastsc(bA.x, sA2, cA2); fastsc(bA.y, sA3, cA3);
            fastsc(tB.x, sB0, cB0); fastsc(tB.y, sB1, cB1);
            fastsc(bB.x, sB2, cB2); fastsc(bB.y, sB3, cB3);

            const v2f c0 = {cA0, cB0}, s0 = {sA0, sB0};
            const v2f c1 = {cA1, cB1}, s1 = {sA1, sB1};
            v2f a00 = c0 * c1, a01 = c0 * s1, a10 = s0 * c1, a11 = s0 * s1;
            #pragma unroll
            for (int r = 0; r < 8; ++r) {
                const v2f b10 = a11, b11 = a10;          // CX(0,1)
                const v2f n00 = c0 * a00 - s0 * b10;     // RY(p0)
                const v2f n01 = c0 * a01 - s0 * b11;
                const v2f n10 = s0 * a00 + c0 * b10;
                const v2f n11 = s0 * a01 + c0 * b11;
                a00 = n00; a01 = n01; a10 = n10; a11 = n11;
            }
            v2f P2[4];
            P2[0] = a00 * a00; P2[1] = a01 * a01; P2[2] = a10 * a10; P2[3] = a11 * a11;
            const v2f t2c = {cA2*cA2, cB2*cB2}, t2s = {sA2*sA2, sB2*sB2};
            const v2f t3c = {cA3*cA3, cB3*cB3}, t3s = {sA3*sA3, sB3*sB3};
            v2f T[4];
            T[0] = t2c * t3c; T[1] = t2c * t3s; T[2] = t2s * t3c; T[3] = t2s * t3s;

            unsigned dA[8], dB[8];
            #pragma unroll
            for (int m = 0; m < 4; ++m) {
                const v2f f0 = P2[m] * T[0], f1 = P2[m] * T[1];
                const v2f f2 = P2[m] * T[2], f3 = P2[m] * T[3];
                dA[2*m]   = packbf(f0.x, f1.x); dA[2*m+1] = packbf(f2.x, f3.x);
                dB[2*m]   = packbf(f0.y, f1.y); dB[2*m+1] = packbf(f2.y, f3.y);
            }
            const v2f sa = s0 * s0, sb2 = t3s;           // sampler: p0, p3
            const v2f na = 1.0f - sa, nb = 1.0f - sb2;
            const v2f e0 = na * nb, e1 = na * sb2, e2 = sa * nb, e3 = sa * sb2;

            unsigned* rowA = buf + (2 * qC) * RSTR;
            unsigned* rowB = rowA + RSTR;
            *reinterpret_cast<uint4*>(rowA + lpC * 8)     = uint4{dA[0], dA[1], dA[2], dA[3]};
            *reinterpret_cast<uint4*>(rowA + lpC * 8 + 4) = uint4{dA[4], dA[5], dA[6], dA[7]};
            *reinterpret_cast<uint2*>(rowA + np * 8 + lpC * 2) =
                uint2{packbf(e0.x, e1.x), packbf(e2.x, e3.x)};
            *reinterpret_cast<uint4*>(rowB + lpC * 8)     = uint4{dB[0], dB[1], dB[2], dB[3]};
            *reinterpret_cast<uint4*>(rowB + lpC * 8 + 4) = uint4{dB[4], dB[5], dB[6], dB[7]};
            *reinterpret_cast<uint2*>(rowB + np * 8 + lpC * 2) =
                uint2{packbf(e0.y, e1.y), packbf(e2.y, e3.y)};
        }

        // ---- prefetch next tile's pixels (in flight across barrier + MFMA) ----
        int lpN = 0, qN = 0; bool actN = false;
        if (t < 3) {
            const int npN = (t + 1 == 3) ? 52 : 48;
            actN = tid < npN * 4;
            const int tt = actN ? tid : 0;
            qN = tt / npN; lpN = tt - qN * npN;
            const int p = 48 * (t + 1) + lpN;
            const int pi = p / 14, pj = p - pi * 14;
            const int off = pi * 56 + pj * 2;
            const float* iA = base + (size_t)(2 * qN) * 784;
            pn[0] = *reinterpret_cast<const float2*>(iA + off);
            pn[1] = *reinterpret_cast<const float2*>(iA + off + 28);
            pn[2] = *reinterpret_cast<const float2*>(iA + 784 + off);
            pn[3] = *reinterpret_cast<const float2*>(iA + 784 + off + 28);
        }

        __syncthreads();    // single barrier per tile (publish buf; release other buf)

        for (int kb = wave; kb < nkb; kb += 4) {
            const short8 a = *reinterpret_cast<const short8*>(buf + aoff + kb * 16);
            const short8 b = *reinterpret_cast<const short8*>(wsb + (size_t)(kbb + kb) * 512 + lane * 8);
            acc = __builtin_amdgcn_mfma_f32_16x16x32_bf16(a, b, acc, 0, 0, 0);
        }

        pc[0] = pn[0]; pc[1] = pn[1]; pc[2] = pn[2]; pc[3] = pn[3];
        lpC = lpN; qC = qN; actC = actN;
    }

    __syncthreads();   // all tile-3 MFMA reads done before reusing lds for epilogue

    // ---- epilogue: combine 4 waves' K-split accs, bias, log-softmax ----
    float* f = reinterpret_cast<float*>(lds);
    f[wave * 256 +   0 + lane] = acc[0];
    f[wave * 256 +  64 + lane] = acc[1];
    f[wave * 256 + 128 + lane] = acc[2];
    f[wave * 256 + 192 + lane] = acc[3];
    __syncthreads();
    if (tid < GIMG * NCLS) {
        const int g = tid / NCLS, c = tid - g * NCLS;
        const int li = ((g >> 2) << 4) + c;   // D: col=lane&15, row=(lane>>4)*4+reg
        const int ri = (g & 3) << 6;
        float v = f[ri + li] + f[256 + ri + li] + f[512 + ri + li] + f[768 + ri + li];
        f[1024 + tid] = v + fc_b[c];
    }
    __syncthreads();
    if (tid < GIMG * NCLS) {
        const int g = tid / NCLS, c = tid - g * NCLS;
        const float* lg = f + 1024 + g * NCLS;
        float m = -1e30f;
        #pragma unroll
        for (int k = 0; k < NCLS; ++k) m = fmaxf(m, lg[k]);
        float ss = 0.f;
        #pragma unroll
        for (int k = 0; k < NCLS; ++k) ss += __expf(lg[k] - m);
        out[(size_t)(img0 + g) * NCLS + c] = lg[c] - m - __logf(ss);
    }
}

extern "C" void kernel_launch(void* const* d_in, const int* in_sizes, int n_in,
                              void* d_out, int out_size, void* d_ws, size_t ws_size,
                              hipStream_t stream) {
    const float* x    = (const float*)d_in[0];
    const float* fc_w = (const float*)d_in[1];
    const float* fc_b = (const float*)d_in[2];
    float* out = (float*)d_out;

    conv_w<<<246, 256, 0, stream>>>(fc_w, (__hip_bfloat16*)d_ws);

    const int B = in_sizes[0] / 784;            // 8192
    const int grid = B / GIMG;                  // 1024
    quanv_mfma<<<grid, 256, 0, stream>>>(x, (const short*)d_ws, fc_b, out);
}